// Round 3
// baseline (434.778 us; speedup 1.0000x reference)
//
#include <hip/hip_runtime.h>

// KNN top-16: B=4, N=8192, D=16, k=16, fp32 in, int32 index out.
// FROZEN key model (validated R11-R18, absmax=0): harness np twin =
//   dot  = BLAS microkernel single-accumulator FMA chain, k = 0..15
//   norm = numpy AVX512 pairwise tree: r_j=m_j+m_{j+8}; q_j=r_j+r_{j+4};
//          fl(fl(q0+q2)+fl(q1+q3))
//   val  = fl( fl(ni + fl(-2*dot)) + nj ), ties -> lower index
// Keys packed u64 = (mono32(key)<<32)|idx: u64 asc == (key asc, idx asc).
// R22: in-wave software pipeline. R21 showed occupancy is GRID-limited
// (512 blocks = 2/CU exactly; 16 waves/CU = 50% cap) -- LDS was never
// the limiter. Theory: per-wave serialization: each t-iter's 10 ds_reads
// sit after prior iter's conditional pbuf ds_writes (compiler can't hoist
// reads over runtime-addressed writes to same LDS array), so every iter
// pays LDS latency with only 4 waves/SIMD to hide it. Fix: explicit
// 2-stage register ping-pong -- load pair P+1 (8 float4 + float2 norm),
// then compute+push pair P. Compile-time alternation, no movs. VGPR
// headroom 56->~128 is free at 2 blocks/CU ((BT_,2) pins cap ~128 per
// R20 evidence: arg2 acts as min blocks/CU on this stack). CAP back to
// 12 (R19-validated; LDS 56.5KB fine at 2 blocks/CU). Push math int-ized.
// Predict: VGPR ~110-128, WRITE_SIZE ~2MB (else spilled->revert),
// dur 366->280-310 profiled if latency-bound; flat if issue-bound.

#define B_    4
#define N_    8192
#define D_    16
#define K_    16
#define SEGS_ 8
#define SEG_  (N_ / SEGS_)   // 1024
#define CH_   8              // rows per staged chunk
#define NCH_  (SEG_ / CH_)   // 128 chunks
#define BT_   512            // 8 waves
#define CAP_  12             // per-lane LDS push-buffer capacity
#define NQ_   (B_ * N_)      // 32768 queries

typedef unsigned long long u64;

// numpy AVX512 pairwise-sum tree for 16 contiguous floats. FROZEN.
__device__ __forceinline__ float np_norm16(const float* __restrict__ p) {
#pragma clang fp contract(off)
  float m[16];
#pragma unroll
  for (int d = 0; d < 16; ++d) m[d] = p[d] * p[d];
  float r[8];
#pragma unroll
  for (int j = 0; j < 8; ++j) r[j] = m[j] + m[j + 8];
  float q[4];
#pragma unroll
  for (int j = 0; j < 4; ++j) q[j] = r[j] + r[j + 4];
  return (q[0] + q[2]) + (q[1] + q[3]);
}

// monotone fp32->u32: uint ascending == float ascending (handles negatives)
__device__ __forceinline__ unsigned mono32(float f) {
  unsigned u = __float_as_uint(f);
  return u ^ ((unsigned)((int)u >> 31) | 0x80000000u);
}

__global__ __launch_bounds__(256) void knn_norms(const float* __restrict__ x,
                                                 float* __restrict__ nrm) {
  int q = blockIdx.x * 256 + threadIdx.x;
  float row[16];
  const float4* xv = (const float4*)(x + (size_t)q * D_);
  float4 a = xv[0], b = xv[1], c = xv[2], d = xv[3];
  row[0]=a.x; row[1]=a.y; row[2]=a.z; row[3]=a.w;
  row[4]=b.x; row[5]=b.y; row[6]=b.z; row[7]=b.w;
  row[8]=c.x; row[9]=c.y; row[10]=c.z; row[11]=c.w;
  row[12]=d.x; row[13]=d.y; row[14]=d.z; row[15]=d.w;
  nrm[q] = np_norm16(row);
}

// ascending insert; '>' keeps earlier (lower idx) on ties
__device__ __forceinline__ void insert16(float d, int j, float (&kd)[K_], int (&ki)[K_]) {
  float cd = d; int ci = j;
#pragma unroll
  for (int p = 0; p < K_; ++p) {
    bool gt = kd[p] > cd;
    float t0 = gt ? cd : kd[p];
    float t1 = gt ? kd[p] : cd;
    int   t2 = gt ? ci : ki[p];
    int   t3 = gt ? ki[p] : ci;
    kd[p] = t0; cd = t1; ki[p] = t2; ci = t3;
  }
}

__device__ __forceinline__ void flushbuf(u64* __restrict__ pbuf, int tid,
                                         int& count, float& thr,
                                         float (&kd)[K_], int (&ki)[K_]) {
#pragma unroll 1
  for (int s = 0; s < CAP_; ++s) {
    if (s < count) {
      u64 e = pbuf[s * BT_ + tid];
      float d = __uint_as_float((unsigned)(e >> 32));
      if (d < thr) {
        int j = (int)(e & 0xffffu);
        insert16(d, j, kd, ki);
        thr = kd[K_ - 1];
      }
    }
  }
  count = 0;
}

// load one candidate pair (2 rows of 16 floats + 2 norms) from LDS into regs
__device__ __forceinline__ void load_pair(const float4* __restrict__ rows,
                                          const float* __restrict__ nnp,
                                          int pr, float4 (&R)[8],
                                          float& n0, float& n1) {
#pragma unroll
  for (int i = 0; i < 8; ++i) R[i] = rows[pr * 8 + i];
  float2 nv = *(const float2*)(nnp + pr * 2);
  n0 = nv.x; n1 = nv.y;
}

// compute 2 distances from regs, conditional push, maybe flush. FROZEN math.
__device__ __forceinline__ void compute_push(const float4 (&R)[8], float nj0, float nj1,
                                             const float (&qa)[D_], float ni, int j0,
                                             u64* __restrict__ pbuf, int tid,
                                             int& count, float& thr,
                                             float (&kd)[K_], int (&ki)[K_]) {
  float c0[16] = {R[0].x,R[0].y,R[0].z,R[0].w, R[1].x,R[1].y,R[1].z,R[1].w,
                  R[2].x,R[2].y,R[2].z,R[2].w, R[3].x,R[3].y,R[3].z,R[3].w};
  float c1[16] = {R[4].x,R[4].y,R[4].z,R[4].w, R[5].x,R[5].y,R[5].z,R[5].w,
                  R[6].x,R[6].y,R[6].z,R[6].w, R[7].x,R[7].y,R[7].z,R[7].w};

  // two independent np-exact FMA chains (k ascending, single accumulator)
  float dot0 = 0.f, dot1 = 0.f;
#pragma unroll
  for (int d = 0; d < D_; ++d) {
    dot0 = __builtin_fmaf(qa[d], c0[d], dot0);
    dot1 = __builtin_fmaf(qa[d], c1[d], dot1);
  }
  float d0, d1;
  {
#pragma clang fp contract(off)
    float i0 = -2.0f * dot0;  float i1 = -2.0f * dot1;
    float u0 = ni + i0;       float u1 = ni + i1;
    d0 = u0 + nj0;            d1 = u1 + nj1;
  }

  if (d0 < thr) {
    pbuf[count * BT_ + tid] = ((u64)__float_as_uint(d0) << 32) | (unsigned)j0;
    ++count;
  }
  if (d1 < thr) {
    pbuf[count * BT_ + tid] = ((u64)__float_as_uint(d1) << 32) | (unsigned)(j0 + 1);
    ++count;
  }
  if (__any(count >= CAP_ - 1)) flushbuf(pbuf, tid, count, thr, kd, ki);
}

__global__ __launch_bounds__(BT_, 2) void knn_fused(const float* __restrict__ x,
                                                    const float* __restrict__ nrm,
                                                    int* __restrict__ out) {
  __shared__ u64 smem[7232];                       // 56.5 KB
  float4* stageR = (float4*)smem;                  // [(w*2+b)*32 + i], 8 KB
  float*  stageN = (float*)(smem + 1024);          // [(w*2+b)*8 + i], 512 B
  u64*    pbuf   = smem + 1088;                    // [s*512 + tid], 48 KB
  // merge overlay (after __syncthreads): smem+1088, (8*16*32)*8 = 32 KB

  const int tid  = threadIdx.x;
  const int w    = tid >> 6;                       // wave id = segment
  const int lane = tid & 63;                       // query-local id
  const int q    = blockIdx.x * 64 + lane;         // global query
  const int bq   = (int)((blockIdx.x * 64u) >> 13);  // batch (block-uniform)
  const int row0 = bq * N_ + w * SEG_;
  const float* __restrict__ cbase = x + (size_t)row0 * D_;
  const float* __restrict__ nbase = nrm + row0;

  float qa[D_];
  {
    const float4* qv = (const float4*)(x + (size_t)q * D_);
    float4 v0 = qv[0], v1 = qv[1], v2 = qv[2], v3 = qv[3];
    qa[0]=v0.x; qa[1]=v0.y; qa[2]=v0.z; qa[3]=v0.w;
    qa[4]=v1.x; qa[5]=v1.y; qa[6]=v1.z; qa[7]=v1.w;
    qa[8]=v2.x; qa[9]=v2.y; qa[10]=v2.z; qa[11]=v2.w;
    qa[12]=v3.x; qa[13]=v3.y; qa[14]=v3.z; qa[15]=v3.w;
  }
  const float ni = nrm[q];

  float kd[K_]; int ki[K_];
#pragma unroll
  for (int p = 0; p < K_; ++p) { kd[p] = 3.4e38f; ki[p] = 0; }
  float thr = 3.4e38f;
  int count = 0;

  // stage chunk 0 (per-wave-private LDS; wave-synchronous, no barrier)
  {
    const float4* gs = (const float4*)cbase;
    if (lane < 32) stageR[(w * 2 + 0) * 32 + lane] = gs[lane];
    if (lane < CH_) stageN[(w * 2 + 0) * CH_ + lane] = nbase[lane];
  }

  // pipeline registers: ping-pong pair sets (compile-time alternation)
  float4 cr[8], nr[8];
  float cn0, cn1, nn0, nn1;
  load_pair(stageR + (w * 2 + 0) * 32, stageN + (w * 2 + 0) * CH_, 0, cr, cn0, cn1);

#pragma unroll 1
  for (int c = 0; c < NCH_; ++c) {
    const int b = c & 1;
    // prefetch chunk c+1 into registers (overlaps compute below)
    float4 p0; float pn = 0.f;
    const bool more = (c + 1 < NCH_);
    if (more) {
      const float4* gs = (const float4*)(cbase + (size_t)(c + 1) * CH_ * D_);
      if (lane < 32) p0 = gs[lane];
      if (lane < CH_) pn = nbase[(c + 1) * CH_ + lane];
    }

    const float4* rows = stageR + (w * 2 + b) * 32;
    const float*  nnp  = stageN + (w * 2 + b) * CH_;
    const int j0 = c * CH_;

    // software pipeline: issue reads for pair P+1, then compute+push pair P
    load_pair(rows, nnp, 1, nr, nn0, nn1);
    compute_push(cr, cn0, cn1, qa, ni, j0 + 0, pbuf, tid, count, thr, kd, ki);
    load_pair(rows, nnp, 2, cr, cn0, cn1);
    compute_push(nr, nn0, nn1, qa, ni, j0 + 2, pbuf, tid, count, thr, kd, ki);
    load_pair(rows, nnp, 3, nr, nn0, nn1);
    compute_push(cr, cn0, cn1, qa, ni, j0 + 4, pbuf, tid, count, thr, kd, ki);
    compute_push(nr, nn0, nn1, qa, ni, j0 + 6, pbuf, tid, count, thr, kd, ki);

    // write prefetched chunk into the other buffer, preload its pair 0
    if (more) {
      if (lane < 32) stageR[(w * 2 + (b ^ 1)) * 32 + lane] = p0;
      if (lane < CH_) stageN[(w * 2 + (b ^ 1)) * CH_ + lane] = pn;
      load_pair(stageR + (w * 2 + (b ^ 1)) * 32,
                stageN + (w * 2 + (b ^ 1)) * CH_, 0, cr, cn0, cn1);
    }
  }
  flushbuf(pbuf, tid, count, thr, kd, ki);

  // ---- publish sorted per-segment top-16 as packed u64, then 8-way merge ----
  // Two half-passes (queries [0,32) then [32,64)) -> 32 KB overlay in pbuf.
  u64* mrg = smem + 1088;                          // [(s*16+p)*32 + m], 32 KB
  const int half = lane >> 5;
  const int lm   = lane & 31;

  __syncthreads();   // all waves done with stage/push regions before overlay
#pragma unroll 1
  for (int h = 0; h < 2; ++h) {
    if (half == h) {
#pragma unroll
      for (int p = 0; p < K_; ++p) {
        mrg[((size_t)w * 16 + p) * 32 + lm] =
            ((u64)mono32(kd[p]) << 32) | (unsigned)(w * SEG_ + ki[p]);
      }
    }
    __syncthreads();

    // merge: 8 lanes per query; 32 queries -> tid<256 (waves 0..3).
    if (tid < 256) {
      const int m  = tid >> 3;                     // query-in-half
      const int s  = tid & 7;                      // my segment stream
      const int qi = h * 32 + m;                   // block-local query
      const int gq = blockIdx.x * 64 + qi;         // global query
      int ptr = 0;
#pragma unroll 1
      for (int r = 0; r < K_; ++r) {
        u64 hd = mrg[((size_t)s * 16 + ptr) * 32 + m];
        u64 mv = hd, o;
        o = __shfl_xor(mv, 1); mv = (o < mv) ? o : mv;
        o = __shfl_xor(mv, 2); mv = (o < mv) ? o : mv;
        o = __shfl_xor(mv, 4); mv = (o < mv) ? o : mv;
        if (hd == mv) ++ptr;                       // exactly one lane advances
        if (s == 0) out[(size_t)gq * K_ + r] = (int)(mv & 0xffffu);
      }
    }
    __syncthreads();                               // overlay reused by pass 2
  }
}

extern "C" void kernel_launch(void* const* d_in, const int* in_sizes, int n_in,
                              void* d_out, int out_size, void* d_ws, size_t ws_size,
                              hipStream_t stream) {
  const float* x = (const float*)d_in[0];
  float* nrm = (float*)d_ws;                       // 128 KB of workspace
  int* out = (int*)d_out;

  knn_norms<<<NQ_ / 256, 256, 0, stream>>>(x, nrm);
  knn_fused<<<NQ_ / 64, BT_, 0, stream>>>(x, nrm, out);
}

// Round 4
// 333.893 us; speedup vs baseline: 1.3021x; 1.3021x over previous
//
#include <hip/hip_runtime.h>

// KNN top-16: B=4, N=8192, D=16, k=16, fp32 in, int32 index out.
// FROZEN key model (validated R11-R18, absmax=0): harness np twin =
//   dot  = BLAS microkernel single-accumulator FMA chain, k = 0..15
//   norm = numpy AVX512 pairwise tree: r_j=m_j+m_{j+8}; q_j=r_j+r_{j+4};
//          fl(fl(q0+q2)+fl(q1+q3))
//   val  = fl( fl(ni + fl(-2*dot)) + nj ), ties -> lower index
// Keys packed u64 = (mono32(key)<<32)|idx: u64 asc == (key asc, idx asc).
// R23: packed-fp32 math. R22 post-mortem: in-wave pipeline FAILED (461us)
// -- conditional pbuf ds_writes between prefetch-read-issue and consume
// force lgkmcnt(0) drains (in-order counter), worse than R21. Reverted
// to R21 loop order. New lever: kernel is ISSUE-bound (366us*86% VALU =
// ~90 VALU-cyc/candidate). v_pk_fma_f32 (VOP3P, gfx90a+) does 2 IEEE
// fp32 FMAs in ONE issue slot; the two candidates of a pair run their
// frozen chains in lo/hi halves bit-exactly. Dot+combine 38->19 issues
// per pair. LDS chunk staged pair-transposed ((c0[d],c1[d]) float2s, 64
// lanes x 2 b32 global + 1 ds_write_b64) so b128 reads deliver packed
// operands directly. Push/flush/merge untouched. Predict: VGPR ~100-120,
// WRITE_SIZE ~2MB, dur 366->300-320 profiled if dot-issue was binding;
// flat -> flush dominates, restructure flush next.

#define B_    4
#define N_    8192
#define D_    16
#define K_    16
#define SEGS_ 8
#define SEG_  (N_ / SEGS_)   // 1024
#define CH_   8              // rows per staged chunk
#define NCH_  (SEG_ / CH_)   // 128 chunks
#define BT_   512            // 8 waves
#define CAP_  12             // per-lane LDS push-buffer capacity
#define NQ_   (B_ * N_)      // 32768 queries

typedef unsigned long long u64;
typedef float v2f __attribute__((ext_vector_type(2)));

// VOP3P packed fp32: one issue slot, two IEEE fp32 ops (per-half == scalar)
__device__ __forceinline__ v2f pk_fma(v2f a, v2f b, v2f c) {
  v2f d;
  asm("v_pk_fma_f32 %0, %1, %2, %3" : "=v"(d) : "v"(a), "v"(b), "v"(c));
  return d;
}
__device__ __forceinline__ v2f pk_mul(v2f a, v2f b) {
  v2f d;
  asm("v_pk_mul_f32 %0, %1, %2" : "=v"(d) : "v"(a), "v"(b));
  return d;
}
__device__ __forceinline__ v2f pk_add(v2f a, v2f b) {
  v2f d;
  asm("v_pk_add_f32 %0, %1, %2" : "=v"(d) : "v"(a), "v"(b));
  return d;
}

// numpy AVX512 pairwise-sum tree for 16 contiguous floats. FROZEN.
__device__ __forceinline__ float np_norm16(const float* __restrict__ p) {
#pragma clang fp contract(off)
  float m[16];
#pragma unroll
  for (int d = 0; d < 16; ++d) m[d] = p[d] * p[d];
  float r[8];
#pragma unroll
  for (int j = 0; j < 8; ++j) r[j] = m[j] + m[j + 8];
  float q[4];
#pragma unroll
  for (int j = 0; j < 4; ++j) q[j] = r[j] + r[j + 4];
  return (q[0] + q[2]) + (q[1] + q[3]);
}

// monotone fp32->u32: uint ascending == float ascending (handles negatives)
__device__ __forceinline__ unsigned mono32(float f) {
  unsigned u = __float_as_uint(f);
  return u ^ ((unsigned)((int)u >> 31) | 0x80000000u);
}

__global__ __launch_bounds__(256) void knn_norms(const float* __restrict__ x,
                                                 float* __restrict__ nrm) {
  int q = blockIdx.x * 256 + threadIdx.x;
  float row[16];
  const float4* xv = (const float4*)(x + (size_t)q * D_);
  float4 a = xv[0], b = xv[1], c = xv[2], d = xv[3];
  row[0]=a.x; row[1]=a.y; row[2]=a.z; row[3]=a.w;
  row[4]=b.x; row[5]=b.y; row[6]=b.z; row[7]=b.w;
  row[8]=c.x; row[9]=c.y; row[10]=c.z; row[11]=c.w;
  row[12]=d.x; row[13]=d.y; row[14]=d.z; row[15]=d.w;
  nrm[q] = np_norm16(row);
}

// ascending insert; '>' keeps earlier (lower idx) on ties
__device__ __forceinline__ void insert16(float d, int j, float (&kd)[K_], int (&ki)[K_]) {
  float cd = d; int ci = j;
#pragma unroll
  for (int p = 0; p < K_; ++p) {
    bool gt = kd[p] > cd;
    float t0 = gt ? cd : kd[p];
    float t1 = gt ? kd[p] : cd;
    int   t2 = gt ? ci : ki[p];
    int   t3 = gt ? ki[p] : ci;
    kd[p] = t0; cd = t1; ki[p] = t2; ci = t3;
  }
}

__device__ __forceinline__ void flushbuf(u64* __restrict__ pbuf, int tid,
                                         int& count, float& thr,
                                         float (&kd)[K_], int (&ki)[K_]) {
#pragma unroll 1
  for (int s = 0; s < CAP_; ++s) {
    if (s < count) {
      u64 e = pbuf[s * BT_ + tid];
      float d = __uint_as_float((unsigned)(e >> 32));
      if (d < thr) {
        int j = (int)(e & 0xffffu);
        insert16(d, j, kd, ki);
        thr = kd[K_ - 1];
      }
    }
  }
  count = 0;
}

__global__ __launch_bounds__(BT_, 2) void knn_fused(const float* __restrict__ x,
                                                    const float* __restrict__ nrm,
                                                    int* __restrict__ out) {
  __shared__ u64 smem[7232];                       // 56.5 KB
  v2f*    stageT = (v2f*)smem;                     // [(w*2+b)*64 + p*16+d], 8 KB
  float*  stageN = (float*)(smem + 1024);          // [(w*2+b)*8 + i], 512 B
  u64*    pbuf   = smem + 1088;                    // [s*512 + tid], 48 KB
  // merge overlay (after __syncthreads): smem+1088, (8*16*32)*8 = 32 KB

  const int tid  = threadIdx.x;
  const int w    = tid >> 6;                       // wave id = segment
  const int lane = tid & 63;                       // query-local id
  const int q    = blockIdx.x * 64 + lane;         // global query
  const int bq   = (int)((blockIdx.x * 64u) >> 13);  // batch (block-uniform)
  const int row0 = bq * N_ + w * SEG_;
  const float* __restrict__ cbase = x + (size_t)row0 * D_;
  const float* __restrict__ nbase = nrm + row0;

  const int p_ = lane >> 4;                        // staging pair slot 0..3
  const int d_ = lane & 15;                        // staging dim 0..15

  // packed query: qq[d] = (qa[d], qa[d]); nip = (ni, ni)
  v2f qq[D_];
  {
    const float4* qv = (const float4*)(x + (size_t)q * D_);
    float4 v0 = qv[0], v1 = qv[1], v2 = qv[2], v3 = qv[3];
    qq[0]=(v2f){v0.x,v0.x}; qq[1]=(v2f){v0.y,v0.y}; qq[2]=(v2f){v0.z,v0.z}; qq[3]=(v2f){v0.w,v0.w};
    qq[4]=(v2f){v1.x,v1.x}; qq[5]=(v2f){v1.y,v1.y}; qq[6]=(v2f){v1.z,v1.z}; qq[7]=(v2f){v1.w,v1.w};
    qq[8]=(v2f){v2.x,v2.x}; qq[9]=(v2f){v2.y,v2.y}; qq[10]=(v2f){v2.z,v2.z}; qq[11]=(v2f){v2.w,v2.w};
    qq[12]=(v2f){v3.x,v3.x}; qq[13]=(v2f){v3.y,v3.y}; qq[14]=(v2f){v3.z,v3.z}; qq[15]=(v2f){v3.w,v3.w};
  }
  const float ni = nrm[q];
  const v2f nip = (v2f){ni, ni};
  const v2f m2  = (v2f){-2.0f, -2.0f};

  float kd[K_]; int ki[K_];
#pragma unroll
  for (int p = 0; p < K_; ++p) { kd[p] = 3.4e38f; ki[p] = 0; }
  float thr = 3.4e38f;
  int count = 0;

  // stage chunk 0 pair-transposed (per-wave-private LDS; wave-synchronous)
  {
    float g0 = cbase[(2 * p_) * D_ + d_];
    float g1 = cbase[(2 * p_ + 1) * D_ + d_];
    stageT[(w * 2 + 0) * 64 + p_ * 16 + d_] = (v2f){g0, g1};
    if (lane < CH_) stageN[(w * 2 + 0) * CH_ + lane] = nbase[lane];
  }

#pragma unroll 1
  for (int c = 0; c < NCH_; ++c) {
    const int b = c & 1;
    // prefetch chunk c+1 into registers (overlaps compute below)
    float pg0 = 0.f, pg1 = 0.f, pn = 0.f;
    const bool more = (c + 1 < NCH_);
    if (more) {
      const float* cb = cbase + (size_t)(c + 1) * CH_ * D_;
      pg0 = cb[(2 * p_) * D_ + d_];
      pg1 = cb[(2 * p_ + 1) * D_ + d_];
      if (lane < CH_) pn = nbase[(c + 1) * CH_ + lane];
    }

    const float4* tp = (const float4*)(stageT + (w * 2 + b) * 64);
    const float*  nW = stageN + (w * 2 + b) * CH_;
    const int j0 = c * CH_;

#pragma unroll 1
    for (int p = 0; p < 4; ++p) {
      // 8 wave-uniform b128 reads: f_i = (c0[2i], c1[2i], c0[2i+1], c1[2i+1])
      float4 f0 = tp[p*8+0], f1 = tp[p*8+1], f2 = tp[p*8+2], f3 = tp[p*8+3];
      float4 f4 = tp[p*8+4], f5 = tp[p*8+5], f6 = tp[p*8+6], f7 = tp[p*8+7];

      // two frozen single-accumulator FMA chains, lo=cand0 / hi=cand1
      v2f acc = (v2f){0.f, 0.f};
      acc = pk_fma(qq[0],  (v2f){f0.x, f0.y}, acc);
      acc = pk_fma(qq[1],  (v2f){f0.z, f0.w}, acc);
      acc = pk_fma(qq[2],  (v2f){f1.x, f1.y}, acc);
      acc = pk_fma(qq[3],  (v2f){f1.z, f1.w}, acc);
      acc = pk_fma(qq[4],  (v2f){f2.x, f2.y}, acc);
      acc = pk_fma(qq[5],  (v2f){f2.z, f2.w}, acc);
      acc = pk_fma(qq[6],  (v2f){f3.x, f3.y}, acc);
      acc = pk_fma(qq[7],  (v2f){f3.z, f3.w}, acc);
      acc = pk_fma(qq[8],  (v2f){f4.x, f4.y}, acc);
      acc = pk_fma(qq[9],  (v2f){f4.z, f4.w}, acc);
      acc = pk_fma(qq[10], (v2f){f5.x, f5.y}, acc);
      acc = pk_fma(qq[11], (v2f){f5.z, f5.w}, acc);
      acc = pk_fma(qq[12], (v2f){f6.x, f6.y}, acc);
      acc = pk_fma(qq[13], (v2f){f6.z, f6.w}, acc);
      acc = pk_fma(qq[14], (v2f){f7.x, f7.y}, acc);
      acc = pk_fma(qq[15], (v2f){f7.z, f7.w}, acc);

      // val = fl( fl(ni + fl(-2*dot)) + nj ), per half (pk ops = scalar IEEE)
      v2f ii  = pk_mul(m2, acc);
      v2f uu  = pk_add(nip, ii);
      v2f njp = *(const v2f*)(nW + 2 * p);
      v2f dd  = pk_add(uu, njp);
      float d0 = dd.x, d1 = dd.y;
      const int j = j0 + 2 * p;

      if (d0 < thr) {
        pbuf[count * BT_ + tid] = ((u64)__float_as_uint(d0) << 32) | (unsigned)j;
        ++count;
      }
      if (d1 < thr) {
        pbuf[count * BT_ + tid] = ((u64)__float_as_uint(d1) << 32) | (unsigned)(j + 1);
        ++count;
      }
      if (__any(count >= CAP_ - 1)) flushbuf(pbuf, tid, count, thr, kd, ki);
    }

    // write prefetched chunk into the other buffer (pair-transposed)
    if (more) {
      stageT[(w * 2 + (b ^ 1)) * 64 + p_ * 16 + d_] = (v2f){pg0, pg1};
      if (lane < CH_) stageN[(w * 2 + (b ^ 1)) * CH_ + lane] = pn;
    }
  }
  flushbuf(pbuf, tid, count, thr, kd, ki);

  // ---- publish sorted per-segment top-16 as packed u64, then 8-way merge ----
  // Two half-passes (queries [0,32) then [32,64)) -> 32 KB overlay in pbuf.
  u64* mrg = smem + 1088;                          // [(s*16+p)*32 + m], 32 KB
  const int half = lane >> 5;
  const int lm   = lane & 31;

  __syncthreads();   // all waves done with stage/push regions before overlay
#pragma unroll 1
  for (int h = 0; h < 2; ++h) {
    if (half == h) {
#pragma unroll
      for (int p = 0; p < K_; ++p) {
        mrg[((size_t)w * 16 + p) * 32 + lm] =
            ((u64)mono32(kd[p]) << 32) | (unsigned)(w * SEG_ + ki[p]);
      }
    }
    __syncthreads();

    // merge: 8 lanes per query; 32 queries -> tid<256 (waves 0..3).
    if (tid < 256) {
      const int m  = tid >> 3;                     // query-in-half
      const int s  = tid & 7;                      // my segment stream
      const int qi = h * 32 + m;                   // block-local query
      const int gq = blockIdx.x * 64 + qi;         // global query
      int ptr = 0;
#pragma unroll 1
      for (int r = 0; r < K_; ++r) {
        u64 hd = mrg[((size_t)s * 16 + ptr) * 32 + m];
        u64 mv = hd, o;
        o = __shfl_xor(mv, 1); mv = (o < mv) ? o : mv;
        o = __shfl_xor(mv, 2); mv = (o < mv) ? o : mv;
        o = __shfl_xor(mv, 4); mv = (o < mv) ? o : mv;
        if (hd == mv) ++ptr;                       // exactly one lane advances
        if (s == 0) out[(size_t)gq * K_ + r] = (int)(mv & 0xffffu);
      }
    }
    __syncthreads();                               // overlay reused by pass 2
  }
}

extern "C" void kernel_launch(void* const* d_in, const int* in_sizes, int n_in,
                              void* d_out, int out_size, void* d_ws, size_t ws_size,
                              hipStream_t stream) {
  const float* x = (const float*)d_in[0];
  float* nrm = (float*)d_ws;                       // 128 KB of workspace
  int* out = (int*)d_out;

  knn_norms<<<NQ_ / 256, 256, 0, stream>>>(x, nrm);
  knn_fused<<<NQ_ / 64, BT_, 0, stream>>>(x, nrm, out);
}